// Round 2
// baseline (132.388 us; speedup 1.0000x reference)
//
#include <hip/hip_runtime.h>
#include <cstdint>
#include <cstddef>

// Problem shape (fixed by setup_inputs): B=256, IN=1024, OUT=1024, 32 pulse bits.
#define BATCH 256
#define IN_F  1024
#define OUT_F 1024

// ---------------------------------------------------------------------------
// decode: 32 pulse floats (0.0/1.0, MSB first) -> one fp32 value (bitcast)
// ---------------------------------------------------------------------------
__device__ __forceinline__ uint32_t decode_bits(const float4* __restrict__ p) {
    uint32_t u = 0;
#pragma unroll
    for (int k = 0; k < 8; ++k) {
        float4 f = p[k];
        // f.* is exactly 0.0f or 1.0f; exponent bit 23 distinguishes.
        u = (u << 1) | ((__float_as_uint(f.x) >> 23) & 1u);
        u = (u << 1) | ((__float_as_uint(f.y) >> 23) & 1u);
        u = (u << 1) | ((__float_as_uint(f.z) >> 23) & 1u);
        u = (u << 1) | ((__float_as_uint(f.w) >> 23) & 1u);
    }
    return u;
}

// x pulses [B, IN, 32] -> x_f [B*IN] fp32
__global__ __launch_bounds__(256) void decode_x_kernel(const float* __restrict__ pulses,
                                                       float* __restrict__ xf) {
    int v = blockIdx.x * 256 + threadIdx.x;        // v in [0, B*IN)
    const float4* p = (const float4*)(pulses + (size_t)v * 32);
    xf[v] = __uint_as_float(decode_bits(p));
}

// w pulses [OUT, IN, 32] -> w_t [IN][OUT] fp32 (transposed for coalesced GEMM reads)
__global__ __launch_bounds__(256) void decode_w_kernel(const float* __restrict__ pulses,
                                                       float* __restrict__ wt) {
    int v = blockIdx.x * 256 + threadIdx.x;        // v = o*IN + i, reads coalesced
    int o = v >> 10;                               // v / IN
    int i = v & (IN_F - 1);                        // v % IN
    const float4* p = (const float4*)(pulses + (size_t)v * 32);
    wt[(size_t)i * OUT_F + o] = __uint_as_float(decode_bits(p));
}

// ---------------------------------------------------------------------------
// GEMM with strict left-to-right fp32 accumulation over i, epilogue encodes
// the fp32 result back to 32 pulse floats.
// CRITICAL: fp contract OFF — the reference semantics are "fp32-rounded mul,
// then fp32-rounded add". An fmac/fma keeps the unrounded product and changes
// low mantissa bits, which flips output pulse bits (R1 failure).
// Block: 256 threads (lane -> o). Each thread computes 4 batch rows.
// Grid: (B/4) * (OUT/256) = 64 * 4 = 256 blocks.
// ---------------------------------------------------------------------------
__global__ __launch_bounds__(256) void gemm_encode_kernel(const float* __restrict__ xf,
                                                          const float* __restrict__ wt,
                                                          float* __restrict__ out) {
#pragma clang fp contract(off)
    const int tid = threadIdx.x;
    const int o  = (blockIdx.x & 3) * 256 + tid;   // output feature
    const int b0 = (blockIdx.x >> 2) * 4;          // first batch row
    const float* __restrict__ x0 = xf + (size_t)b0 * IN_F;
    const float* __restrict__ x1 = x0 + IN_F;
    const float* __restrict__ x2 = x1 + IN_F;
    const float* __restrict__ x3 = x2 + IN_F;

    // scan init: acc = prods[0]  (exact; avoids 0 + (-0.0) sign issue)
    float w0 = wt[o];
    float a0 = x0[0] * w0;
    float a1 = x1[0] * w0;
    float a2 = x2[0] * w0;
    float a3 = x3[0] * w0;

#pragma unroll 8
    for (int i = 1; i < IN_F; ++i) {
        float w = wt[(size_t)i * OUT_F + o];
        // fp32-rounded multiply, then strictly ordered fp32 add (no FMA!)
        a0 = a0 + (x0[i] * w);
        a1 = a1 + (x1[i] * w);
        a2 = a2 + (x2[i] * w);
        a3 = a3 + (x3[i] * w);
    }

    float acc[4] = {a0, a1, a2, a3};
#pragma unroll
    for (int r = 0; r < 4; ++r) {
        uint32_t u = __float_as_uint(acc[r]);
        float4* dst = (float4*)(out + ((size_t)(b0 + r) * OUT_F + o) * 32);
#pragma unroll
        for (int k = 0; k < 8; ++k) {
            float4 f;
            f.x = (float)((u >> (31 - 4 * k)) & 1u);
            f.y = (float)((u >> (30 - 4 * k)) & 1u);
            f.z = (float)((u >> (29 - 4 * k)) & 1u);
            f.w = (float)((u >> (28 - 4 * k)) & 1u);
            dst[k] = f;
        }
    }
}

extern "C" void kernel_launch(void* const* d_in, const int* in_sizes, int n_in,
                              void* d_out, int out_size, void* d_ws, size_t ws_size,
                              hipStream_t stream) {
    const float* x_pulses = (const float*)d_in[0];   // [B, IN, 32]
    const float* w_pulses = (const float*)d_in[1];   // [OUT, IN, 32]
    float* out = (float*)d_out;                      // [B, OUT, 32]

    // workspace: x_f [B*IN] fp32 (1 MB), then w_t [IN*OUT] fp32 (4 MB)
    float* xf = (float*)d_ws;
    float* wt = xf + (size_t)BATCH * IN_F;

    decode_x_kernel<<<(BATCH * IN_F) / 256, 256, 0, stream>>>(x_pulses, xf);
    decode_w_kernel<<<(OUT_F * IN_F) / 256, 256, 0, stream>>>(w_pulses, wt);
    gemm_encode_kernel<<<(BATCH / 4) * (OUT_F / 256), 256, 0, stream>>>(xf, wt, out);
}

// Round 3
// 102.085 us; speedup vs baseline: 1.2968x; 1.2968x over previous
//
#include <hip/hip_runtime.h>
#include <cstdint>
#include <cstddef>

// Reference semantics: per-element fp32-rounded multiply, then a strictly
// sequential left-to-right fp32 add chain. FMA contraction changes low
// mantissa bits and flips output pulse bits -> keep contract OFF globally.
#pragma clang fp contract(off)

// Problem shape (fixed by setup_inputs): B=256, IN=1024, OUT=1024, 32 pulse bits.
#define BATCH 256
#define IN_F  1024
#define OUT_F 1024

// ---------------------------------------------------------------------------
// decode: 32 pulse floats (0.0/1.0, MSB first) -> one fp32 value (bitcast)
// ---------------------------------------------------------------------------
__device__ __forceinline__ uint32_t decode_bits(const float4* __restrict__ p) {
    uint32_t u = 0;
#pragma unroll
    for (int k = 0; k < 8; ++k) {
        float4 f = p[k];
        // f.* is exactly 0.0f or 1.0f; exponent bit 23 distinguishes.
        u = (u << 1) | ((__float_as_uint(f.x) >> 23) & 1u);
        u = (u << 1) | ((__float_as_uint(f.y) >> 23) & 1u);
        u = (u << 1) | ((__float_as_uint(f.z) >> 23) & 1u);
        u = (u << 1) | ((__float_as_uint(f.w) >> 23) & 1u);
    }
    return u;
}

// x pulses [B, IN, 32] -> x_f [B*IN] fp32
__global__ __launch_bounds__(256) void decode_x_kernel(const float* __restrict__ pulses,
                                                       float* __restrict__ xf) {
    int v = blockIdx.x * 256 + threadIdx.x;        // v in [0, B*IN)
    const float4* p = (const float4*)(pulses + (size_t)v * 32);
    xf[v] = __uint_as_float(decode_bits(p));
}

// w pulses [OUT, IN, 32] -> wt2 layout [IN/16][OUT][16] fp32:
// thread o's 16 consecutive-i weights are contiguous -> float4 loads in gemm.
__global__ __launch_bounds__(256) void decode_w_kernel(const float* __restrict__ pulses,
                                                       float* __restrict__ wt2) {
    int v = blockIdx.x * 256 + threadIdx.x;        // v = o*IN + i, reads coalesced
    int o = v >> 10;                               // v / IN
    int i = v & (IN_F - 1);                        // v % IN
    const float4* p = (const float4*)(pulses + (size_t)v * 32);
    float val = __uint_as_float(decode_bits(p));
    wt2[((size_t)(i >> 4) * OUT_F + o) * 16 + (i & 15)] = val;
}

// ---------------------------------------------------------------------------
// GEMM: one output (b, o) per thread, strict left-to-right accumulation.
// Block: 512 threads = 8 waves; wave -> one batch row, lane -> o (coalesced w).
// Grid: (OUT/64) * (B/8) = 16 * 32 = 512 blocks.
// x rows staged in LDS (broadcast reads); w software-pipelined in 16-wide
// float4 register blocks (ping-pong, prefetch distance 1).
// ---------------------------------------------------------------------------
__global__ __launch_bounds__(512) void gemm_encode_kernel(const float* __restrict__ xf,
                                                          const float* __restrict__ wt2,
                                                          float* __restrict__ out) {
#pragma clang fp contract(off)
    const int tid  = threadIdx.x;
    const int lane = tid & 63;
    const int wv   = tid >> 6;                     // wave id = local batch row
    const int o    = (blockIdx.x & 15) * 64 + lane;
    const int b0   = (blockIdx.x >> 4) * 8;        // block's first batch row
    const int b    = b0 + wv;

    // ---- stage 8 x-rows (32 KB) into LDS, coalesced ----
    __shared__ float xs[8 * IN_F];
    {
        const float4* src = (const float4*)(xf + (size_t)b0 * IN_F);
        float4* dst = (float4*)xs;
#pragma unroll
        for (int k = 0; k < 4; ++k) dst[tid + k * 512] = src[tid + k * 512];
    }
    __syncthreads();

    const float* xrow  = xs + wv * IN_F;
    const float* wbase = wt2 + (size_t)o * 16;     // + r * (OUT_F*16) per i-block

    auto ldw = [&](int r, float4* dst) {
        const float4* p = (const float4*)(wbase + (size_t)r * (OUT_F * 16));
#pragma unroll
        for (int k = 0; k < 4; ++k) dst[k] = p[k];
    };

    float acc;
    auto consume = [&](int r, const float4* w) {
        const float4* xr4 = (const float4*)(xrow + r * 16);
#pragma unroll
        for (int q = 0; q < 4; ++q) {
            float4 xv = xr4[q];
            float4 wq = w[q];
            acc = acc + (xv.x * wq.x);
            acc = acc + (xv.y * wq.y);
            acc = acc + (xv.z * wq.z);
            acc = acc + (xv.w * wq.w);
        }
    };

    float4 wreg[4], wn[4];
    ldw(0, wreg);
    ldw(1, wn);

    // i-block 0: init acc = x[0]*w[0] (scan init), then i=1..15 in order
    {
        const float4* xr4 = (const float4*)xrow;
        float4 xv = xr4[0];
        acc = xv.x * wreg[0].x;
        acc = acc + (xv.y * wreg[0].y);
        acc = acc + (xv.z * wreg[0].z);
        acc = acc + (xv.w * wreg[0].w);
#pragma unroll
        for (int q = 1; q < 4; ++q) {
            xv = xr4[q];
            float4 wq = wreg[q];
            acc = acc + (xv.x * wq.x);
            acc = acc + (xv.y * wq.y);
            acc = acc + (xv.z * wq.z);
            acc = acc + (xv.w * wq.w);
        }
    }

    // blocks 1..62, ping-pong with prefetch distance 1 (16 i ahead)
    for (int ib = 1; ib <= 61; ib += 2) {
        ldw(ib + 1, wreg);
        consume(ib, wn);
        ldw(ib + 2, wn);
        consume(ib + 1, wreg);
    }
    consume(63, wn);                               // final block

    // ---- encode acc back to 32 pulse floats ----
    uint32_t u = __float_as_uint(acc);
    float4* dstp = (float4*)(out + ((size_t)b * OUT_F + o) * 32);
#pragma unroll
    for (int k = 0; k < 8; ++k) {
        float4 f;
        f.x = (float)((u >> (31 - 4 * k)) & 1u);
        f.y = (float)((u >> (30 - 4 * k)) & 1u);
        f.z = (float)((u >> (29 - 4 * k)) & 1u);
        f.w = (float)((u >> (28 - 4 * k)) & 1u);
        dstp[k] = f;
    }
}

extern "C" void kernel_launch(void* const* d_in, const int* in_sizes, int n_in,
                              void* d_out, int out_size, void* d_ws, size_t ws_size,
                              hipStream_t stream) {
    const float* x_pulses = (const float*)d_in[0];   // [B, IN, 32]
    const float* w_pulses = (const float*)d_in[1];   // [OUT, IN, 32]
    float* out = (float*)d_out;                      // [B, OUT, 32]

    // workspace: x_f [B*IN] fp32 (1 MB), then w_t2 [IN/16][OUT][16] fp32 (4 MB)
    float* xf  = (float*)d_ws;
    float* wt2 = xf + (size_t)BATCH * IN_F;

    decode_x_kernel<<<(BATCH * IN_F) / 256, 256, 0, stream>>>(x_pulses, xf);
    decode_w_kernel<<<(OUT_F * IN_F) / 256, 256, 0, stream>>>(w_pulses, wt2);
    gemm_encode_kernel<<<(OUT_F / 64) * (BATCH / 8), 512, 0, stream>>>(xf, wt2, out);
}

// Round 4
// 68.343 us; speedup vs baseline: 1.9371x; 1.4937x over previous
//
#include <hip/hip_runtime.h>
#include <cstdint>
#include <cstddef>

// Reference semantics: per-element fp32-rounded multiply, then a strictly
// sequential left-to-right fp32 add chain. FMA contraction changes low
// mantissa bits and flips output pulse bits -> keep contract OFF globally.
#pragma clang fp contract(off)

#define BATCH 256
#define IN_F  1024
#define OUT_F 1024

// ---------------------------------------------------------------------------
// decode: 32 pulse floats (0.0/1.0, MSB first) -> fp32 bit pattern
// ---------------------------------------------------------------------------
__device__ __forceinline__ uint32_t decode_bits(const float4* __restrict__ p) {
    uint32_t u = 0;
#pragma unroll
    for (int k = 0; k < 8; ++k) {
        float4 f = p[k];
        u = (u << 1) | ((__float_as_uint(f.x) >> 23) & 1u);
        u = (u << 1) | ((__float_as_uint(f.y) >> 23) & 1u);
        u = (u << 1) | ((__float_as_uint(f.z) >> 23) & 1u);
        u = (u << 1) | ((__float_as_uint(f.w) >> 23) & 1u);
    }
    return u;
}

// x pulses [B, IN, 32] -> x_f [B][IN] fp32 row-major
__global__ __launch_bounds__(256) void decode_x_kernel(const float* __restrict__ pulses,
                                                       float* __restrict__ xf) {
    int v = blockIdx.x * 256 + threadIdx.x;
    const float4* p = (const float4*)(pulses + (size_t)v * 32);
    xf[v] = __uint_as_float(decode_bits(p));
}

// w pulses [OUT, IN, 32] -> wt3 layout [IN/32][OUT][8 q][4 d] fp32 (dwords).
// i = sc*32 + q*4 + d. This is the "pre-swizzle friendly" layout the gemm's
// global_load_lds staging reads from (rule #21: linear LDS dest + swizzled
// global source).
__global__ __launch_bounds__(256) void decode_w_kernel(const float* __restrict__ pulses,
                                                       float* __restrict__ wt3) {
    int v = blockIdx.x * 256 + threadIdx.x;        // v = o*IN + i, reads coalesced
    int o = v >> 10;
    int i = v & (IN_F - 1);
    const float4* p = (const float4*)(pulses + (size_t)v * 32);
    float val = __uint_as_float(decode_bits(p));
    size_t idx = (((((size_t)(i >> 5)) << 10) + o) * 8 + ((i >> 2) & 7)) * 4 + (i & 3);
    wt3[idx] = val;
}

// ---------------------------------------------------------------------------
// GEMM: block = 512 threads = 8 waves; covers 64 o (lanes) x 16 b rows
// (wave wv handles rows wv and wv+8, R=2). Grid = 16 o-tiles x 16 b-tiles
// = 256 blocks = 1 per CU.
// w staged in LDS per 128-i chunk (double-buffered) via global_load_lds;
// LDS layout per 32-i sub-chunk: [o=64][slot=8] float4 with slot = q^(o&7)
// -> every ds_read_b128 hits all 32 banks evenly (b128 floor).
// x staged per chunk in LDS, read as uniform broadcast b128.
// Strict left-to-right fp32 accumulation over i; mul then add, no FMA.
// ---------------------------------------------------------------------------
__global__ __launch_bounds__(512, 1) void gemm_encode_kernel(const float* __restrict__ xf,
                                                             const float* __restrict__ wt3,
                                                             float* __restrict__ out) {
#pragma clang fp contract(off)
    const int tid  = threadIdx.x;
    const int lane = tid & 63;
    const int wv   = tid >> 6;
    const int ot   = blockIdx.x & 15;              // o-tile
    const int bt   = blockIdx.x >> 4;              // b-tile
    const int o_g  = ot * 64 + lane;
    const int b0   = bt * 16;
    const int om   = lane & 7;

    __shared__ float4 wl[2][4][64][8];             // 64 KB: [buf][sc][o][slot]
    __shared__ float4 xb[2][16][32];               // 16 KB: [buf][row][i4]

    // staging lane mapping (linear LDS dest): thread t -> (o = t>>3, s = t&7)
    const int o_st = wv * 8 + (lane >> 3);
    const int q_st = (lane & 7) ^ (lane >> 3);     // content q for physical slot s

    auto stage = [&](int bb, int c) {
        // x chunk: rows b0..b0+15, i in [c*128, c*128+128). 8 KB, one shot.
        {
            const char* g = (const char*)(xf + ((size_t)(b0 + wv * 2 + (lane >> 5)) << 10)
                                             + (c << 7)) + (size_t)(lane & 31) * 16;
            char* d = (char*)(&xb[bb][0][0]) + wv * 1024;
            __builtin_amdgcn_global_load_lds(
                (const __attribute__((address_space(1))) void*)g,
                (__attribute__((address_space(3))) void*)d, 16, 0, 0);
        }
        // w chunk: 4 sub-chunks of 32 i. 32 KB, 4 shots.
#pragma unroll
        for (int sc = 0; sc < 4; ++sc) {
            int sc_g = c * 4 + sc;
            size_t dw = (((((size_t)sc_g) << 10) + (ot * 64 + o_st)) * 8 + q_st) * 4;
            const char* g = (const char*)(wt3 + dw);
            char* d = (char*)(&wl[bb][sc][0][0]) + wv * 1024;
            __builtin_amdgcn_global_load_lds(
                (const __attribute__((address_space(1))) void*)g,
                (__attribute__((address_space(3))) void*)d, 16, 0, 0);
        }
    };

    float acc0 = 0.0f, acc1 = 0.0f;

    auto compute = [&](int bb, bool first) {
#pragma unroll
        for (int sc = 0; sc < 4; ++sc) {
            float4 w4[8];
#pragma unroll
            for (int q = 0; q < 8; ++q) w4[q] = wl[bb][sc][lane][q ^ om];
#pragma unroll
            for (int q = 0; q < 8; ++q) {
                float4 xa = xb[bb][wv][sc * 8 + q];       // row wv      (uniform)
                float4 xc = xb[bb][wv + 8][sc * 8 + q];   // row wv + 8  (uniform)
                if (first && sc == 0 && q == 0) {
                    acc0 = xa.x * w4[0].x;                // scan init: acc = prods[0]
                    acc1 = xc.x * w4[0].x;
                } else {
                    acc0 = acc0 + (xa.x * w4[q].x);
                    acc1 = acc1 + (xc.x * w4[q].x);
                }
                acc0 = acc0 + (xa.y * w4[q].y);
                acc1 = acc1 + (xc.y * w4[q].y);
                acc0 = acc0 + (xa.z * w4[q].z);
                acc1 = acc1 + (xc.z * w4[q].z);
                acc0 = acc0 + (xa.w * w4[q].w);
                acc1 = acc1 + (xc.w * w4[q].w);
            }
        }
    };

    // prologue
    stage(0, 0);
    __syncthreads();                                // drains vmcnt before use

    int cur = 0;
#pragma unroll 1
    for (int c = 0; c < 8; ++c) {
        if (c < 7) stage(cur ^ 1, c + 1);           // issue next-chunk loads early
        compute(cur, c == 0);
        __syncthreads();                            // vmcnt+lgkm drain + barrier
        cur ^= 1;
    }

    // ---- encode both accumulators back to 32 pulse floats ----
    const float accs[2] = {acc0, acc1};
#pragma unroll
    for (int r = 0; r < 2; ++r) {
        uint32_t u = __float_as_uint(accs[r]);
        int b = b0 + wv + r * 8;
        float4* dstp = (float4*)(out + (((size_t)b << 10) + o_g) * 32);
#pragma unroll
        for (int k = 0; k < 8; ++k) {
            float4 f;
            f.x = (float)((u >> (31 - 4 * k)) & 1u);
            f.y = (float)((u >> (30 - 4 * k)) & 1u);
            f.z = (float)((u >> (29 - 4 * k)) & 1u);
            f.w = (float)((u >> (28 - 4 * k)) & 1u);
            dstp[k] = f;
        }
    }
}

extern "C" void kernel_launch(void* const* d_in, const int* in_sizes, int n_in,
                              void* d_out, int out_size, void* d_ws, size_t ws_size,
                              hipStream_t stream) {
    const float* x_pulses = (const float*)d_in[0];   // [B, IN, 32]
    const float* w_pulses = (const float*)d_in[1];   // [OUT, IN, 32]
    float* out = (float*)d_out;                      // [B, OUT, 32]

    float* xf  = (float*)d_ws;                       // 1 MB
    float* wt3 = xf + (size_t)BATCH * IN_F;          // 4 MB

    decode_x_kernel<<<(BATCH * IN_F) / 256, 256, 0, stream>>>(x_pulses, xf);
    decode_w_kernel<<<(OUT_F * IN_F) / 256, 256, 0, stream>>>(w_pulses, wt3);
    gemm_encode_kernel<<<256, 512, 0, stream>>>(xf, wt3, out);
}